// Round 8
// baseline (37.978 us; speedup 1.0000x reference)
//
#include <hip/hip_runtime.h>
#include <math.h>

// UnrolledMeanShift: B=2, D=32, H=W=256, K=5x5, 3 iterations.
// R8 = R7 (packed-fp16 named-SSA, 2-lane channel split, DPP pair-combine)
// + 2 vertically-adjacent pixels per thread: the 6x5 shared window needs
// 60 ds_read_b128/iter instead of 100 for the two pixels (-40% DS traffic).
// Row stride 21 words / plane stride 421 words decorrelate banks for the
// pair-lane (+32B), plane (+80B) and pyy-group (+32B) offsets.
// NO per-thread arrays (R4-R6 lesson: aggregates >= 25 entries go to scratch).

typedef _Float16 h2  __attribute__((ext_vector_type(2)));
typedef _Float16 h8  __attribute__((ext_vector_type(8)));
typedef unsigned int u4v __attribute__((ext_vector_type(4)));

constexpr int Dch  = 32;
constexpr int HH   = 256;
constexpr int WW   = 256;
constexpr int PADp = 2;
constexpr int BH   = 16;
constexpr int BW   = 16;
constexpr int TH   = BH + 2 * PADp;   // 20 halo rows
constexpr int TWd  = BW + 2 * PADp;   // 20 halo cols (data)
constexpr int RSTR = 21;              // padded row stride (u4v words)
constexpr int PSTR = TH * RSTR + 1;   // 421 words plane stride (16B each)
constexpr int ITERS = 3;
constexpr int HWp  = HH * WW;
constexpr int NTHR = 256;             // 2 ch-halves x 128 pixel-pairs

__device__ __forceinline__ float fdot2f(h2 a, h2 b, float c) {
    return __builtin_amdgcn_fdot2(a, b, c, false);
}

__device__ __forceinline__ float EXP2F(float x) {
#if __has_builtin(__builtin_amdgcn_exp2f)
    return __builtin_amdgcn_exp2f(x);
#else
    return __expf(x * 0.69314718055994531f);
#endif
}

// value from lane^1 (quad_perm [1,0,3,2]) — pure VALU, no LDS pipe
__device__ __forceinline__ float qswap(float x) {
#if __has_builtin(__builtin_amdgcn_mov_dpp)
    return __int_as_float(
        __builtin_amdgcn_mov_dpp(__float_as_int(x), 0xB1, 0xF, 0xF, true));
#else
    return __shfl_xor(x, 1, 64);
#endif
}

__device__ __forceinline__ h2 as_h2(unsigned int x) {
    return __builtin_bit_cast(h2, x);
}

__global__ __launch_bounds__(NTHR, 2)
void meanshift_kernel(const float* __restrict__ E,
                      const float* __restrict__ lbw,
                      float* __restrict__ out)
{
    __shared__ u4v tile[4 * PSTR];       // 4 planes x 421 words = 26.9 KB

    const int bz   = blockIdx.z;
    const int oh   = blockIdx.y * BH - PADp;
    const int ow   = blockIdx.x * BW - PADp;
    const int tid  = threadIdx.x;
    const int half = tid & 1;            // which 16 channels
    const int idx  = tid >> 1;           // 0..127 pixel-pair
    const int px   = idx & (BW - 1);     // 0..15
    const int pyy  = idx >> 4;           // 0..7
    const int py0  = 2 * pyy;            // upper pixel row (A); B = py0+1
    const int c0   = 2 * half;           // first of my two planes

    const float bwv   = log1pf(__expf(lbw[0]));   // softplus
    const float cc2   = 1.0f / (2.0f * bwv * bwv);
    const float negNC = -cc2 * 1.44269504f;       // w = exp2(negNC * dist^2)

    const float* Eb = E + (size_t)bz * Dch * HWp;

    // ---- stage halo tile into LDS as fp16 (R3/R7-proven, padded layout) ----
    for (int job = tid; job < 4 * (TH * TWd); job += NTHR) {
        const int cc = job / (TH * TWd);
        const int p  = job - cc * (TH * TWd);
        const int tr = p / TWd;
        const int tc = p - tr * TWd;
        const int gh = oh + tr;
        const int gw = ow + tc;
        h8 v;
        if ((unsigned)gh < (unsigned)HH && (unsigned)gw < (unsigned)WW) {
            const float* p0 = Eb + (size_t)(8 * cc) * HWp + gh * WW + gw;
            #pragma unroll
            for (int k = 0; k < 8; ++k) v[k] = (_Float16)p0[k * HWp];
        } else {
            #pragma unroll
            for (int k = 0; k < 8; ++k) v[k] = (_Float16)0.f;
        }
        tile[cc * PSTR + tr * RSTR + tc] = __builtin_bit_cast(u4v, v);
    }
    __syncthreads();

    const u4v* __restrict__ tA = tile + c0 * PSTR;
    const u4v* __restrict__ tB = tA + PSTR;

    // ---- init z for both pixels (center of each window) ----
    const int mypA = (py0 + 2) * RSTR + (px + 2);
    const int mypB = mypA + RSTR;
    h2 zA0, zA1, zA2, zA3, zA4, zA5, zA6, zA7;
    h2 zB0, zB1, zB2, zB3, zB4, zB5, zB6, zB7;
    {
        const u4v ca = tA[mypA], cb = tB[mypA];
        zA0 = as_h2(ca[0]); zA1 = as_h2(ca[1]); zA2 = as_h2(ca[2]); zA3 = as_h2(ca[3]);
        zA4 = as_h2(cb[0]); zA5 = as_h2(cb[1]); zA6 = as_h2(cb[2]); zA7 = as_h2(cb[3]);
        const u4v da = tA[mypB], db = tB[mypB];
        zB0 = as_h2(da[0]); zB1 = as_h2(da[1]); zB2 = as_h2(da[2]); zB3 = as_h2(da[3]);
        zB4 = as_h2(db[0]); zB5 = as_h2(db[1]); zB6 = as_h2(db[2]); zB7 = as_h2(db[3]);
    }

    float* Ob = out + (size_t)bz * Dch * HWp;
    const int offA   = (oh + PADp + py0) * WW + (ow + PADp + px);
    const int chbase = 16 * half;

#define NBODY(RA, RB, ZP, NP, DEN) do {                                       \
        const h2 pa0 = as_h2(RA[0]), pa1 = as_h2(RA[1]);                      \
        const h2 pa2 = as_h2(RA[2]), pa3 = as_h2(RA[3]);                      \
        const h2 pb0 = as_h2(RB[0]), pb1 = as_h2(RB[1]);                      \
        const h2 pb2 = as_h2(RB[2]), pb3 = as_h2(RB[3]);                      \
        const h2 e0 = pa0 - ZP##0, e1 = pa1 - ZP##1;                          \
        const h2 e2 = pa2 - ZP##2, e3 = pa3 - ZP##3;                          \
        const h2 f0 = pb0 - ZP##4, f1 = pb1 - ZP##5;                          \
        const h2 f2 = pb2 - ZP##6, f3 = pb3 - ZP##7;                          \
        float s0 = fdot2f(e0, e0, 0.f);                                       \
        s0 = fdot2f(e1, e1, s0); s0 = fdot2f(e2, e2, s0);                     \
        s0 = fdot2f(e3, e3, s0);                                              \
        float s1 = fdot2f(f0, f0, 0.f);                                       \
        s1 = fdot2f(f1, f1, s1); s1 = fdot2f(f2, f2, s1);                     \
        s1 = fdot2f(f3, f3, s1);                                              \
        const float dp   = s0 + s1;                                           \
        const float dist = dp + qswap(dp);                                    \
        const float w    = EXP2F(dist * negNC);                               \
        DEN += w;                                                             \
        const _Float16 wh = (_Float16)w;                                      \
        const h2 w2v = {wh, wh};                                              \
        NP##0 += pa0 * w2v; NP##1 += pa1 * w2v;                               \
        NP##2 += pa2 * w2v; NP##3 += pa3 * w2v;                               \
        NP##4 += pb0 * w2v; NP##5 += pb1 * w2v;                               \
        NP##6 += pb2 * w2v; NP##7 += pb3 * w2v;                               \
    } while (0)

    #pragma unroll 1
    for (int it = 0; it < ITERS; ++it) {
        h2 nA0 = {(_Float16)0.f, (_Float16)0.f};
        h2 nA1 = nA0, nA2 = nA0, nA3 = nA0, nA4 = nA0, nA5 = nA0, nA6 = nA0, nA7 = nA0;
        h2 nB0 = nA0, nB1 = nA0, nB2 = nA0, nB3 = nA0, nB4 = nA0, nB5 = nA0, nB6 = nA0, nB7 = nA0;
        float denA = 0.f, denB = 0.f;

        #pragma unroll 1
        for (int di = 0; di < 6; ++di) {
            const int rwb = (py0 + di) * RSTR + px;
            const u4v qa0 = tA[rwb + 0], qa1 = tA[rwb + 1], qa2 = tA[rwb + 2];
            const u4v qa3 = tA[rwb + 3], qa4 = tA[rwb + 4];
            const u4v qb0 = tB[rwb + 0], qb1 = tB[rwb + 1], qb2 = tB[rwb + 2];
            const u4v qb3 = tB[rwb + 3], qb4 = tB[rwb + 4];
            if (di != 5) {                       // rows 0..4 feed pixel A
                NBODY(qa0, qb0, zA, nA, denA);
                NBODY(qa1, qb1, zA, nA, denA);
                NBODY(qa2, qb2, zA, nA, denA);
                NBODY(qa3, qb3, zA, nA, denA);
                NBODY(qa4, qb4, zA, nA, denA);
            }
            if (di != 0) {                       // rows 1..5 feed pixel B
                NBODY(qa0, qb0, zB, nB, denB);
                NBODY(qa1, qb1, zB, nB, denB);
                NBODY(qa2, qb2, zB, nB, denB);
                NBODY(qa3, qb3, zB, nB, denB);
                NBODY(qa4, qb4, zB, nB, denB);
            }
        }

        const float invA = 1.0f / (denA + 1e-6f);
        const float invB = 1.0f / (denB + 1e-6f);
        if (it == ITERS - 1) {
#define WR(IDX, NV, EL, OFF, INV) \
            Ob[(size_t)(chbase + (IDX)) * HWp + (OFF)] = (float)NV[EL] * (INV)
            WR(0,  nA0, 0, offA, invA); WR(1,  nA0, 1, offA, invA);
            WR(2,  nA1, 0, offA, invA); WR(3,  nA1, 1, offA, invA);
            WR(4,  nA2, 0, offA, invA); WR(5,  nA2, 1, offA, invA);
            WR(6,  nA3, 0, offA, invA); WR(7,  nA3, 1, offA, invA);
            WR(8,  nA4, 0, offA, invA); WR(9,  nA4, 1, offA, invA);
            WR(10, nA5, 0, offA, invA); WR(11, nA5, 1, offA, invA);
            WR(12, nA6, 0, offA, invA); WR(13, nA6, 1, offA, invA);
            WR(14, nA7, 0, offA, invA); WR(15, nA7, 1, offA, invA);
            WR(0,  nB0, 0, offA + WW, invB); WR(1,  nB0, 1, offA + WW, invB);
            WR(2,  nB1, 0, offA + WW, invB); WR(3,  nB1, 1, offA + WW, invB);
            WR(4,  nB2, 0, offA + WW, invB); WR(5,  nB2, 1, offA + WW, invB);
            WR(6,  nB3, 0, offA + WW, invB); WR(7,  nB3, 1, offA + WW, invB);
            WR(8,  nB4, 0, offA + WW, invB); WR(9,  nB4, 1, offA + WW, invB);
            WR(10, nB5, 0, offA + WW, invB); WR(11, nB5, 1, offA + WW, invB);
            WR(12, nB6, 0, offA + WW, invB); WR(13, nB6, 1, offA + WW, invB);
            WR(14, nB7, 0, offA + WW, invB); WR(15, nB7, 1, offA + WW, invB);
#undef WR
        } else {
            const _Float16 ihA = (_Float16)invA;
            const _Float16 ihB = (_Float16)invB;
            const h2 ivA = {ihA, ihA};
            const h2 ivB = {ihB, ihB};
            zA0 = nA0 * ivA; zA1 = nA1 * ivA; zA2 = nA2 * ivA; zA3 = nA3 * ivA;
            zA4 = nA4 * ivA; zA5 = nA5 * ivA; zA6 = nA6 * ivA; zA7 = nA7 * ivA;
            zB0 = nB0 * ivB; zB1 = nB1 * ivB; zB2 = nB2 * ivB; zB3 = nB3 * ivB;
            zB4 = nB4 * ivB; zB5 = nB5 * ivB; zB6 = nB6 * ivB; zB7 = nB7 * ivB;
        }
    }
#undef NBODY
}

extern "C" void kernel_launch(void* const* d_in, const int* in_sizes, int n_in,
                              void* d_out, int out_size, void* d_ws, size_t ws_size,
                              hipStream_t stream) {
    const float* E   = (const float*)d_in[0];
    const float* lbw = (const float*)d_in[1];
    float* out       = (float*)d_out;

    const int B = in_sizes[0] / (Dch * HWp);       // = 2
    dim3 grid(WW / BW, HH / BH, B);                // (16,16,2) = 512 blocks
    dim3 block(NTHR, 1, 1);                        // 256 threads (2 px each)
    hipLaunchKernelGGL(meanshift_kernel, grid, block, 0, stream, E, lbw, out);
}